// Round 1
// baseline (769.429 us; speedup 1.0000x reference)
//
#include <hip/hip_runtime.h>

#define NN 10000
#define EE 100000
#define ETOT 110000   // EE + NN self loops
#define INC 256
#define HH 6
#define CC 128
#define FF 768        // HH*CC
#define BB 64
#define BN_EPS 1e-5f

// ---------- float <-> order-preserving uint encoding (for atomicMax on float) ----------
__device__ __forceinline__ unsigned fenc(float v){
  unsigned u = __float_as_uint(v);
  return (u & 0x80000000u) ? ~u : (u | 0x80000000u);
}
__device__ __forceinline__ float fdec(unsigned u){
  return (u & 0x80000000u) ? __uint_as_float(u & 0x7FFFFFFFu) : __uint_as_float(~u);
}
#define FENC_NEG_INF 0x007FFFFFu   // fenc(-inf)

// ---------- CSR build ----------
__global__ __launch_bounds__(256) void count_deg(const int* __restrict__ adj, int* __restrict__ deg){
  int k = blockIdx.x*256 + threadIdx.x;
  if(k >= ETOT) return;
  int d = (k < EE) ? adj[EE + k] : (k - EE);
  atomicAdd(deg + d, 1);
}

__global__ __launch_bounds__(1024) void scan_deg(const int* __restrict__ deg,
                                                 int* __restrict__ row_start,
                                                 int* __restrict__ pos){
  __shared__ int buf[1024];
  __shared__ int carry;
  int t = threadIdx.x;
  if(t == 0) carry = 0;
  __syncthreads();
  for(int base = 0; base < NN; base += 1024){
    int i = base + t;
    int v = (i < NN) ? deg[i] : 0;
    buf[t] = v;
    __syncthreads();
    for(int off = 1; off < 1024; off <<= 1){
      int x = (t >= off) ? buf[t - off] : 0;
      __syncthreads();
      buf[t] += x;
      __syncthreads();
    }
    int incl = buf[t];
    int c = carry;
    if(i < NN){ row_start[i] = c + incl - v; pos[i] = c + incl - v; }
    __syncthreads();
    if(t == 1023) carry = c + buf[1023];
    __syncthreads();
  }
  if(t == 0) row_start[NN] = carry;
}

__global__ __launch_bounds__(256) void scatter_edges(const int* __restrict__ adj,
                                                     int* __restrict__ pos,
                                                     int* __restrict__ csr_src,
                                                     int* __restrict__ csr_eid){
  int k = blockIdx.x*256 + threadIdx.x;
  if(k >= ETOT) return;
  int s, d;
  if(k < EE){ s = adj[k]; d = adj[EE + k]; } else { s = k - EE; d = s; }
  int i = atomicAdd(pos + d, 1);
  csr_src[i] = s;
  csr_eid[i] = k;
}

// ---------- fp32 tiled GEMM: C[M,Nc] = normA(A[M,K]) @ B[K,Nc] (+bias) ----------
// normA: per-column (feature) scale/shift folded into the A-tile load (BN fusion).
__global__ __launch_bounds__(256) void gemm64(const float* __restrict__ A,
                                              const float* __restrict__ Bm,
                                              float* __restrict__ Cm,
                                              int M, int K, int Nc,
                                              const float* __restrict__ ascale,
                                              const float* __restrict__ ashift,
                                              const float* __restrict__ bias){
  __shared__ float As[16][65];
  __shared__ float Bs[16][64];
  int tid = threadIdx.x;
  int bm = blockIdx.y * 64, bn = blockIdx.x * 64;
  int ty = tid >> 4, tx = tid & 15;
  float acc[4][4];
  #pragma unroll
  for(int i=0;i<4;i++)
    #pragma unroll
    for(int j=0;j<4;j++) acc[i][j] = 0.f;

  int ar = tid >> 2, ak = (tid & 3) << 2;
  int br = tid >> 4, bc = (tid & 15) << 2;

  for(int k0 = 0; k0 < K; k0 += 16){
    float4 av;
    int gr = bm + ar;
    if(gr < M) av = *(const float4*)(A + (size_t)gr*K + k0 + ak);
    else       av = make_float4(0.f,0.f,0.f,0.f);
    if(ascale){
      av.x = fmaf(av.x, ascale[k0+ak+0], ashift[k0+ak+0]);
      av.y = fmaf(av.y, ascale[k0+ak+1], ashift[k0+ak+1]);
      av.z = fmaf(av.z, ascale[k0+ak+2], ashift[k0+ak+2]);
      av.w = fmaf(av.w, ascale[k0+ak+3], ashift[k0+ak+3]);
    }
    float4 bv = *(const float4*)(Bm + (size_t)(k0 + br)*Nc + bn + bc);
    __syncthreads();
    As[ak+0][ar] = av.x; As[ak+1][ar] = av.y; As[ak+2][ar] = av.z; As[ak+3][ar] = av.w;
    *(float4*)&Bs[br][bc] = bv;
    __syncthreads();
    #pragma unroll
    for(int kk = 0; kk < 16; kk++){
      float a[4], b[4];
      #pragma unroll
      for(int i=0;i<4;i++){ a[i] = As[kk][(ty<<2)+i]; b[i] = Bs[kk][(tx<<2)+i]; }
      #pragma unroll
      for(int i=0;i<4;i++)
        #pragma unroll
        for(int j=0;j<4;j++) acc[i][j] = fmaf(a[i], b[j], acc[i][j]);
    }
  }
  #pragma unroll
  for(int i=0;i<4;i++){
    int gr = bm + (ty<<2) + i;
    if(gr < M){
      int gc = bn + (tx<<2);
      float4 o;
      o.x = acc[i][0]; o.y = acc[i][1]; o.z = acc[i][2]; o.w = acc[i][3];
      if(bias){ o.x += bias[gc+0]; o.y += bias[gc+1]; o.z += bias[gc+2]; o.w += bias[gc+3]; }
      *(float4*)(Cm + (size_t)gr*Nc + gc) = o;
    }
  }
}

// ---------- per-node attention dots: a_s[n,h] = sum_c hx[n,h,c]*att_s[h,c] ----------
__global__ __launch_bounds__(256) void att_dots(const float* __restrict__ hx,
                                                const float* __restrict__ atts,
                                                const float* __restrict__ attd,
                                                float* __restrict__ a_s,
                                                float* __restrict__ a_d){
  int n = blockIdx.x, t = threadIdx.x;
  const float* row = hx + (size_t)n*FF;
  float v0 = row[t], v1 = row[t+256], v2 = row[t+512];
  float s[3] = { v0*atts[t], v1*atts[t+256], v2*atts[t+512] };
  float dd[3] = { v0*attd[t], v1*attd[t+256], v2*attd[t+512] };
  #pragma unroll
  for(int off = 1; off < 64; off <<= 1){
    #pragma unroll
    for(int j=0;j<3;j++){ s[j] += __shfl_xor(s[j], off); dd[j] += __shfl_xor(dd[j], off); }
  }
  __shared__ float red[4][6];
  int wave = t >> 6, lane = t & 63;
  if(lane == 0){
    red[wave][0]=s[0]; red[wave][1]=s[1]; red[wave][2]=s[2];
    red[wave][3]=dd[0]; red[wave][4]=dd[1]; red[wave][5]=dd[2];
  }
  __syncthreads();
  if(t < 12){
    int pair = t / 6, r = t % 6;
    float val = red[pair*2][r] + red[pair*2+1][r];
    int j = (r < 3) ? r : r - 3;
    int h = 2*j + pair;      // waves 0-1 cover h={0,2,4}, waves 2-3 cover h={1,3,5}
    if(r < 3) a_s[n*6 + h] = val; else a_d[n*6 + h] = val;
  }
}

// ---------- attention softmax (edge-parallel) ----------
__global__ __launch_bounds__(256) void init_ms(unsigned* __restrict__ mEnc, float* __restrict__ ssum){
  int i = blockIdx.x*256 + threadIdx.x;
  if(i < NN*6){ mEnc[i] = FENC_NEG_INF; ssum[i] = 0.f; }
}

__global__ __launch_bounds__(256) void edge_phase1(const int* __restrict__ adj,
                                                   const float* __restrict__ a_s,
                                                   const float* __restrict__ a_d,
                                                   float* __restrict__ ebuf,
                                                   unsigned* __restrict__ mEnc){
  int k = blockIdx.x*256 + threadIdx.x;
  if(k >= ETOT) return;
  int s, d;
  if(k < EE){ s = adj[k]; d = adj[EE + k]; } else { s = k - EE; d = s; }
  #pragma unroll
  for(int h = 0; h < 6; h++){
    float v = a_s[s*6 + h] + a_d[d*6 + h];
    v = v > 0.f ? v : 0.2f * v;              // leaky_relu(0.2)
    ebuf[(size_t)k*6 + h] = v;
    atomicMax(mEnc + d*6 + h, fenc(v));
  }
}

__global__ __launch_bounds__(256) void edge_phase2(const int* __restrict__ adj,
                                                   float* __restrict__ ebuf,
                                                   const unsigned* __restrict__ mEnc,
                                                   float* __restrict__ ssum){
  int k = blockIdx.x*256 + threadIdx.x;
  if(k >= ETOT) return;
  int d = (k < EE) ? adj[EE + k] : (k - EE);
  #pragma unroll
  for(int h = 0; h < 6; h++){
    float m = fdec(mEnc[d*6 + h]);
    float w = __expf(ebuf[(size_t)k*6 + h] - m);
    ebuf[(size_t)k*6 + h] = w;
    atomicAdd(ssum + d*6 + h, w);
  }
}

// ---------- CSR aggregation: y[n,:] = relu( sum_e alpha*hx[src] + bias ) ----------
__global__ __launch_bounds__(256) void aggregate(const float* __restrict__ hx,
                                                 const float* __restrict__ wbuf,
                                                 const float* __restrict__ ssum,
                                                 const int* __restrict__ row_start,
                                                 const int* __restrict__ csr_src,
                                                 const int* __restrict__ csr_eid,
                                                 const float* __restrict__ bias,
                                                 float* __restrict__ y){
  int n = blockIdx.x, t = threadIdx.x;
  int e0 = row_start[n], e1 = row_start[n+1];
  int h0 = t >> 7, h1 = (t + 256) >> 7, h2 = (t + 512) >> 7;
  float acc0 = 0.f, acc1 = 0.f, acc2 = 0.f;
  for(int i = e0; i < e1; i++){
    int s = csr_src[i];
    int k = csr_eid[i];
    const float* row = hx + (size_t)s*FF;
    const float* wk = wbuf + (size_t)k*6;
    float w0 = wk[h0], w1 = wk[h1], w2 = wk[h2];
    acc0 = fmaf(w0, row[t],     acc0);
    acc1 = fmaf(w1, row[t+256], acc1);
    acc2 = fmaf(w2, row[t+512], acc2);
  }
  float i0 = 1.f/ssum[n*6+h0], i1 = 1.f/ssum[n*6+h1], i2 = 1.f/ssum[n*6+h2];
  float v0 = acc0*i0 + bias[t];
  float v1 = acc1*i1 + bias[t+256];
  float v2 = acc2*i2 + bias[t+512];
  y[(size_t)n*FF + t]       = v0 > 0.f ? v0 : 0.f;
  y[(size_t)n*FF + t + 256] = v1 > 0.f ? v1 : 0.f;
  y[(size_t)n*FF + t + 512] = v2 > 0.f ? v2 : 0.f;
}

// ---------- batch-norm stats ----------
__global__ __launch_bounds__(256) void bn_stats(const float* __restrict__ y,
                                                float* __restrict__ sums,
                                                float* __restrict__ sumsq){
  int t = threadIdx.x;
  float s0=0.f,s1=0.f,s2=0.f,q0=0.f,q1=0.f,q2=0.f;
  for(int n = blockIdx.x; n < NN; n += gridDim.x){
    const float* row = y + (size_t)n*FF;
    float v0 = row[t], v1 = row[t+256], v2 = row[t+512];
    s0 += v0; q0 += v0*v0;
    s1 += v1; q1 += v1*v1;
    s2 += v2; q2 += v2*v2;
  }
  atomicAdd(sums + t,       s0); atomicAdd(sumsq + t,       q0);
  atomicAdd(sums + t + 256, s1); atomicAdd(sumsq + t + 256, q1);
  atomicAdd(sums + t + 512, s2); atomicAdd(sumsq + t + 512, q2);
}

__global__ __launch_bounds__(256) void bn_final(const float* __restrict__ sums,
                                                const float* __restrict__ sumsq,
                                                const float* __restrict__ g,
                                                const float* __restrict__ be,
                                                float* __restrict__ scale,
                                                float* __restrict__ shift){
  int f = blockIdx.x*256 + threadIdx.x;
  if(f >= FF) return;
  float mu  = sums[f] * (1.f/NN);
  float var = sumsq[f] * (1.f/NN) - mu*mu;
  float sc = g[f] * rsqrtf(var + BN_EPS);
  scale[f] = sc;
  shift[f] = be[f] - mu*sc;
}

// ---------- final segment max pool ----------
__global__ __launch_bounds__(256) void init_out(unsigned* __restrict__ outEnc){
  int i = blockIdx.x*256 + threadIdx.x;
  if(i < BB*CC) outEnc[i] = FENC_NEG_INF;
}
__global__ __launch_bounds__(256) void segmax(const float* __restrict__ z,
                                              const int* __restrict__ ibatch,
                                              unsigned* __restrict__ outEnc){
  int idx = blockIdx.x*256 + threadIdx.x;
  if(idx >= NN*CC) return;
  int n = idx >> 7, c = idx & 127;
  atomicMax(outEnc + ibatch[n]*CC + c, fenc(z[idx]));
}
__global__ __launch_bounds__(256) void decode_out(const unsigned* __restrict__ outEnc,
                                                  float* __restrict__ out){
  int i = blockIdx.x*256 + threadIdx.x;
  if(i < BB*CC) out[i] = fdec(outEnc[i]);
}

extern "C" void kernel_launch(void* const* d_in, const int* in_sizes, int n_in,
                              void* d_out, int out_size, void* d_ws, size_t ws_size,
                              hipStream_t stream){
  const float* feat  = (const float*)d_in[0];
  const int*   adj   = (const int*)d_in[1];
  const int*   ibatch= (const int*)d_in[2];
  const float* W1    = (const float*)d_in[3];
  const float* atts1 = (const float*)d_in[4];
  const float* attd1 = (const float*)d_in[5];
  const float* b1    = (const float*)d_in[6];
  const float* g1    = (const float*)d_in[7];
  const float* be1   = (const float*)d_in[8];
  const float* W2    = (const float*)d_in[9];
  const float* atts2 = (const float*)d_in[10];
  const float* attd2 = (const float*)d_in[11];
  const float* b2    = (const float*)d_in[12];
  const float* g2    = (const float*)d_in[13];
  const float* be2   = (const float*)d_in[14];
  const float* linW  = (const float*)d_in[15];
  const float* linb  = (const float*)d_in[16];
  float* out = (float*)d_out;

  size_t off = 0;
  auto alloc = [&](size_t bytes) -> void* {
    void* p = (char*)d_ws + off;
    off += (bytes + 255) & ~(size_t)255;
    return p;
  };
  float*    hx      = (float*)alloc((size_t)NN*FF*4);
  float*    y       = (float*)alloc((size_t)NN*FF*4);
  float*    z       = (float*)alloc((size_t)NN*CC*4);
  float*    a_s     = (float*)alloc((size_t)NN*6*4);
  float*    a_d     = (float*)alloc((size_t)NN*6*4);
  float*    ebuf    = (float*)alloc((size_t)ETOT*6*4);
  unsigned* mEnc    = (unsigned*)alloc((size_t)NN*6*4);
  float*    ssum    = (float*)alloc((size_t)NN*6*4);
  int*      deg     = (int*)alloc((size_t)NN*4);
  int*      row_start=(int*)alloc((size_t)(NN+1)*4);
  int*      pos     = (int*)alloc((size_t)NN*4);
  int*      csr_src = (int*)alloc((size_t)ETOT*4);
  int*      csr_eid = (int*)alloc((size_t)ETOT*4);
  float*    sums    = (float*)alloc((size_t)2*FF*4);
  float*    sumsq   = sums + FF;
  float*    scale   = (float*)alloc((size_t)FF*4);
  float*    shift   = (float*)alloc((size_t)FF*4);
  unsigned* outEnc  = (unsigned*)alloc((size_t)BB*CC*4);

  const int EB = (ETOT + 255)/256;

  // CSR build (dst-grouped incoming edge lists, incl. self loops)
  hipMemsetAsync(deg, 0, NN*4, stream);
  count_deg<<<EB,256,0,stream>>>(adj, deg);
  scan_deg<<<1,1024,0,stream>>>(deg, row_start, pos);
  scatter_edges<<<EB,256,0,stream>>>(adj, pos, csr_src, csr_eid);

  // ---- conv1 ----
  gemm64<<<dim3(FF/64,(NN+63)/64),256,0,stream>>>(feat, W1, hx, NN, INC, FF, nullptr, nullptr, nullptr);
  att_dots<<<NN,256,0,stream>>>(hx, atts1, attd1, a_s, a_d);
  init_ms<<<(NN*6+255)/256,256,0,stream>>>(mEnc, ssum);
  edge_phase1<<<EB,256,0,stream>>>(adj, a_s, a_d, ebuf, mEnc);
  edge_phase2<<<EB,256,0,stream>>>(adj, ebuf, mEnc, ssum);
  aggregate<<<NN,256,0,stream>>>(hx, ebuf, ssum, row_start, csr_src, csr_eid, b1, y);
  hipMemsetAsync(sums, 0, 2*FF*4, stream);
  bn_stats<<<256,256,0,stream>>>(y, sums, sumsq);
  bn_final<<<3,256,0,stream>>>(sums, sumsq, g1, be1, scale, shift);

  // ---- conv2 (BN1 folded into GEMM A-load) ----
  gemm64<<<dim3(FF/64,(NN+63)/64),256,0,stream>>>(y, W2, hx, NN, FF, FF, scale, shift, nullptr);
  att_dots<<<NN,256,0,stream>>>(hx, atts2, attd2, a_s, a_d);
  init_ms<<<(NN*6+255)/256,256,0,stream>>>(mEnc, ssum);
  edge_phase1<<<EB,256,0,stream>>>(adj, a_s, a_d, ebuf, mEnc);
  edge_phase2<<<EB,256,0,stream>>>(adj, ebuf, mEnc, ssum);
  aggregate<<<NN,256,0,stream>>>(hx, ebuf, ssum, row_start, csr_src, csr_eid, b2, y);
  hipMemsetAsync(sums, 0, 2*FF*4, stream);
  bn_stats<<<256,256,0,stream>>>(y, sums, sumsq);
  bn_final<<<3,256,0,stream>>>(sums, sumsq, g2, be2, scale, shift);

  // ---- linear head (BN2 folded) + global max pool ----
  gemm64<<<dim3(CC/64,(NN+63)/64),256,0,stream>>>(y, linW, z, NN, FF, CC, scale, shift, linb);
  init_out<<<(BB*CC+255)/256,256,0,stream>>>(outEnc);
  segmax<<<(NN*CC+255)/256,256,0,stream>>>(z, ibatch, outEnc);
  decode_out<<<(BB*CC+255)/256,256,0,stream>>>(outEnc, out);
}

// Round 2
// 557.224 us; speedup vs baseline: 1.3808x; 1.3808x over previous
//
#include <hip/hip_runtime.h>

#define NN 10000
#define MP 10112      // 79*128, padded row count for MFMA GEMM A-tiles
#define EE 100000
#define ETOT 110000   // EE + NN self loops
#define INC 256
#define HH 6
#define CC 128
#define FF 768        // HH*CC
#define BB 64
#define BN_EPS 1e-5f

typedef unsigned short ushort_t;
typedef __attribute__((ext_vector_type(8))) short bf16x8;
typedef __attribute__((ext_vector_type(4))) float f32x4;
#define AS1 __attribute__((address_space(1)))
#define AS3 __attribute__((address_space(3)))

// ---------- float <-> order-preserving uint encoding (for atomicMax on float) ----------
__device__ __forceinline__ unsigned fenc(float v){
  unsigned u = __float_as_uint(v);
  return (u & 0x80000000u) ? ~u : (u | 0x80000000u);
}
__device__ __forceinline__ float fdec(unsigned u){
  return (u & 0x80000000u) ? __uint_as_float(u & 0x7FFFFFFFu) : __uint_as_float(~u);
}
#define FENC_NEG_INF 0x007FFFFFu   // fenc(-inf)

__device__ __forceinline__ ushort_t f2bf(float v){   // RNE fp32 -> bf16
  unsigned u = __float_as_uint(v);
  u += 0x7FFFu + ((u >> 16) & 1u);
  return (ushort_t)(u >> 16);
}

// ---------- CSR build ----------
__global__ __launch_bounds__(256) void count_deg(const int* __restrict__ adj, int* __restrict__ deg){
  int k = blockIdx.x*256 + threadIdx.x;
  if(k >= ETOT) return;
  int d = (k < EE) ? adj[EE + k] : (k - EE);
  atomicAdd(deg + d, 1);
}

__global__ __launch_bounds__(1024) void scan_deg(const int* __restrict__ deg,
                                                 int* __restrict__ row_start,
                                                 int* __restrict__ pos){
  __shared__ int buf[1024];
  __shared__ int carry;
  int t = threadIdx.x;
  if(t == 0) carry = 0;
  __syncthreads();
  for(int base = 0; base < NN; base += 1024){
    int i = base + t;
    int v = (i < NN) ? deg[i] : 0;
    buf[t] = v;
    __syncthreads();
    for(int off = 1; off < 1024; off <<= 1){
      int x = (t >= off) ? buf[t - off] : 0;
      __syncthreads();
      buf[t] += x;
      __syncthreads();
    }
    int incl = buf[t];
    int c = carry;
    if(i < NN){ row_start[i] = c + incl - v; pos[i] = c + incl - v; }
    __syncthreads();
    if(t == 1023) carry = c + buf[1023];
    __syncthreads();
  }
  if(t == 0) row_start[NN] = carry;
}

__global__ __launch_bounds__(256) void scatter_edges(const int* __restrict__ adj,
                                                     int* __restrict__ pos,
                                                     int* __restrict__ csr_src,
                                                     int* __restrict__ csr_eid){
  int k = blockIdx.x*256 + threadIdx.x;
  if(k >= ETOT) return;
  int s, d;
  if(k < EE){ s = adj[k]; d = adj[EE + k]; } else { s = k - EE; d = s; }
  int i = atomicAdd(pos + d, 1);
  csr_src[i] = s;
  csr_eid[i] = k;
}

// ---------- fp32 -> bf16 converts ----------
__global__ __launch_bounds__(256) void conv_bf16(const float* __restrict__ in,
                                                 ushort_t* __restrict__ out, int n4){
  int i = blockIdx.x*256 + threadIdx.x;
  if(i >= n4) return;
  float4 v = ((const float4*)in)[i];
  ushort4 o;
  o.x = f2bf(v.x); o.y = f2bf(v.y); o.z = f2bf(v.z); o.w = f2bf(v.w);
  ((ushort4*)out)[i] = o;
}

// out = bf16(in*scale[f] + shift[f]), f = feature index (BN fold)
__global__ __launch_bounds__(256) void conv_bf16_affine(const float* __restrict__ in,
                                                        const float* __restrict__ sc,
                                                        const float* __restrict__ sh,
                                                        ushort_t* __restrict__ out, int n4){
  int i = blockIdx.x*256 + threadIdx.x;
  if(i >= n4) return;
  int f = (i << 2) % FF;
  float4 v = ((const float4*)in)[i];
  float4 s = *(const float4*)(sc + f);
  float4 t = *(const float4*)(sh + f);
  ushort4 o;
  o.x = f2bf(fmaf(v.x, s.x, t.x));
  o.y = f2bf(fmaf(v.y, s.y, t.y));
  o.z = f2bf(fmaf(v.z, s.z, t.z));
  o.w = f2bf(fmaf(v.w, s.w, t.w));
  ((ushort4*)out)[i] = o;
}

// ---------- W[K,N] fp32 -> Wt[N,K] bf16 (LDS 32x32 tile transpose) ----------
__global__ __launch_bounds__(256) void transpose_bf(const float* __restrict__ in,
                                                    ushort_t* __restrict__ out,
                                                    int K, int N){
  __shared__ ushort_t tile[32][33];
  int kb = blockIdx.y*32, nb = blockIdx.x*32;
  int tx = threadIdx.x & 31, ty = threadIdx.x >> 5;   // ty 0..7
  #pragma unroll
  for(int r = ty; r < 32; r += 8)
    tile[tx][r] = f2bf(in[(size_t)(kb + r)*N + nb + tx]);
  __syncthreads();
  #pragma unroll
  for(int r = ty; r < 32; r += 8)
    out[(size_t)(nb + r)*K + kb + tx] = tile[r][tx];
}

// ---------- bf16 MFMA GEMM: C[M,N] = A[MP,K] * Bt[N,K]^T (+bias) ----------
// m97 structure: 128x128 tile, BK=32, global_load_lds width 16, 4 waves x 4x4 frags.
__global__ __launch_bounds__(256) void gemm_bt(const ushort_t* __restrict__ A,
                                               const ushort_t* __restrict__ Bt,
                                               float* __restrict__ C,
                                               int M, int N, int K,
                                               const float* __restrict__ bias){
  __shared__ ushort_t As[128*32];
  __shared__ ushort_t Bs[128*32];
  int tid = threadIdx.x;
  int bm = blockIdx.y*128, bn = blockIdx.x*128;
  int w = tid >> 6, lane = tid & 63;
  int wr = (w >> 1)*64, wc = (w & 1)*64;
  int quad = lane >> 4, l15 = lane & 15;

  f32x4 acc[4][4];
  #pragma unroll
  for(int i=0;i<4;i++)
    #pragma unroll
    for(int j=0;j<4;j++) acc[i][j] = (f32x4){0.f,0.f,0.f,0.f};

  // staging chunks: thread t handles 16B chunks t and t+256 of each 8KB tile
  int ch0 = tid, ch1 = tid + 256;
  int ar0 = ch0 >> 2, ac0 = (ch0 & 3) << 3;
  int ar1 = ch1 >> 2, ac1 = (ch1 & 3) << 3;
  const ushort_t* Ag0 = A + (size_t)(bm + ar0)*K + ac0;
  const ushort_t* Ag1 = A + (size_t)(bm + ar1)*K + ac1;
  const ushort_t* Bg0 = Bt + (size_t)(bn + ar0)*K + ac0;
  const ushort_t* Bg1 = Bt + (size_t)(bn + ar1)*K + ac1;

  for(int k0 = 0; k0 < K; k0 += 32){
    __builtin_amdgcn_global_load_lds((const AS1 unsigned int*)(Ag0 + k0),
                                     (AS3 unsigned int*)(As + ch0*8), 16, 0, 0);
    __builtin_amdgcn_global_load_lds((const AS1 unsigned int*)(Ag1 + k0),
                                     (AS3 unsigned int*)(As + ch1*8), 16, 0, 0);
    __builtin_amdgcn_global_load_lds((const AS1 unsigned int*)(Bg0 + k0),
                                     (AS3 unsigned int*)(Bs + ch0*8), 16, 0, 0);
    __builtin_amdgcn_global_load_lds((const AS1 unsigned int*)(Bg1 + k0),
                                     (AS3 unsigned int*)(Bs + ch1*8), 16, 0, 0);
    __syncthreads();   // drains vmcnt -> LDS tiles ready

    bf16x8 a[4], b[4];
    #pragma unroll
    for(int i=0;i<4;i++) a[i] = *(const bf16x8*)&As[(wr + i*16 + l15)*32 + quad*8];
    #pragma unroll
    for(int j=0;j<4;j++) b[j] = *(const bf16x8*)&Bs[(wc + j*16 + l15)*32 + quad*8];
    #pragma unroll
    for(int i=0;i<4;i++)
      #pragma unroll
      for(int j=0;j<4;j++)
        acc[i][j] = __builtin_amdgcn_mfma_f32_16x16x32_bf16(a[i], b[j], acc[i][j], 0, 0, 0);
    __syncthreads();   // all reads done before next overwrite
  }

  // epilogue: C/D layout col=lane&15, row=quad*4+reg
  #pragma unroll
  for(int j=0;j<4;j++){
    int gc = bn + wc + j*16 + l15;
    float bv = bias ? bias[gc] : 0.f;
    #pragma unroll
    for(int i=0;i<4;i++){
      #pragma unroll
      for(int r=0;r<4;r++){
        int gr = bm + wr + i*16 + quad*4 + r;
        if(gr < M) C[(size_t)gr*N + gc] = acc[i][j][r] + bv;
      }
    }
  }
}

// ---------- per-node attention dots: a_s[n,h] = sum_c hx[n,h,c]*att_s[h,c] ----------
__global__ __launch_bounds__(256) void att_dots(const float* __restrict__ hx,
                                                const float* __restrict__ atts,
                                                const float* __restrict__ attd,
                                                float* __restrict__ a_s,
                                                float* __restrict__ a_d){
  int n = blockIdx.x, t = threadIdx.x;
  const float* row = hx + (size_t)n*FF;
  float v0 = row[t], v1 = row[t+256], v2 = row[t+512];
  float s[3] = { v0*atts[t], v1*atts[t+256], v2*atts[t+512] };
  float dd[3] = { v0*attd[t], v1*attd[t+256], v2*attd[t+512] };
  #pragma unroll
  for(int off = 1; off < 64; off <<= 1){
    #pragma unroll
    for(int j=0;j<3;j++){ s[j] += __shfl_xor(s[j], off); dd[j] += __shfl_xor(dd[j], off); }
  }
  __shared__ float red[4][6];
  int wave = t >> 6, lane = t & 63;
  if(lane == 0){
    red[wave][0]=s[0]; red[wave][1]=s[1]; red[wave][2]=s[2];
    red[wave][3]=dd[0]; red[wave][4]=dd[1]; red[wave][5]=dd[2];
  }
  __syncthreads();
  if(t < 12){
    int pair = t / 6, r = t % 6;
    float val = red[pair*2][r] + red[pair*2+1][r];
    int j = (r < 3) ? r : r - 3;
    int h = 2*j + pair;
    if(r < 3) a_s[n*6 + h] = val; else a_d[n*6 + h] = val;
  }
}

// ---------- attention softmax (edge-parallel) ----------
__global__ __launch_bounds__(256) void init_ms(unsigned* __restrict__ mEnc, float* __restrict__ ssum){
  int i = blockIdx.x*256 + threadIdx.x;
  if(i < NN*6){ mEnc[i] = FENC_NEG_INF; ssum[i] = 0.f; }
}

__global__ __launch_bounds__(256) void edge_phase1(const int* __restrict__ adj,
                                                   const float* __restrict__ a_s,
                                                   const float* __restrict__ a_d,
                                                   float* __restrict__ ebuf,
                                                   unsigned* __restrict__ mEnc){
  int k = blockIdx.x*256 + threadIdx.x;
  if(k >= ETOT) return;
  int s, d;
  if(k < EE){ s = adj[k]; d = adj[EE + k]; } else { s = k - EE; d = s; }
  #pragma unroll
  for(int h = 0; h < 6; h++){
    float v = a_s[s*6 + h] + a_d[d*6 + h];
    v = v > 0.f ? v : 0.2f * v;
    ebuf[(size_t)k*6 + h] = v;
    atomicMax(mEnc + d*6 + h, fenc(v));
  }
}

__global__ __launch_bounds__(256) void edge_phase2(const int* __restrict__ adj,
                                                   float* __restrict__ ebuf,
                                                   const unsigned* __restrict__ mEnc,
                                                   float* __restrict__ ssum){
  int k = blockIdx.x*256 + threadIdx.x;
  if(k >= ETOT) return;
  int d = (k < EE) ? adj[EE + k] : (k - EE);
  #pragma unroll
  for(int h = 0; h < 6; h++){
    float m = fdec(mEnc[d*6 + h]);
    float w = __expf(ebuf[(size_t)k*6 + h] - m);
    ebuf[(size_t)k*6 + h] = w;
    atomicAdd(ssum + d*6 + h, w);
  }
}

// ---------- CSR aggregation: y[n,:] = relu( sum_e alpha*hx[src] + bias ) ----------
__global__ __launch_bounds__(256) void aggregate(const float* __restrict__ hx,
                                                 const float* __restrict__ wbuf,
                                                 const float* __restrict__ ssum,
                                                 const int* __restrict__ row_start,
                                                 const int* __restrict__ csr_src,
                                                 const int* __restrict__ csr_eid,
                                                 const float* __restrict__ bias,
                                                 float* __restrict__ y){
  int n = blockIdx.x, t = threadIdx.x;
  int e0 = row_start[n], e1 = row_start[n+1];
  int h0 = t >> 7, h1 = (t + 256) >> 7, h2 = (t + 512) >> 7;
  float acc0 = 0.f, acc1 = 0.f, acc2 = 0.f;
  for(int i = e0; i < e1; i++){
    int s = csr_src[i];
    int k = csr_eid[i];
    const float* row = hx + (size_t)s*FF;
    const float* wk = wbuf + (size_t)k*6;
    float w0 = wk[h0], w1 = wk[h1], w2 = wk[h2];
    acc0 = fmaf(w0, row[t],     acc0);
    acc1 = fmaf(w1, row[t+256], acc1);
    acc2 = fmaf(w2, row[t+512], acc2);
  }
  float i0 = 1.f/ssum[n*6+h0], i1 = 1.f/ssum[n*6+h1], i2 = 1.f/ssum[n*6+h2];
  float v0 = acc0*i0 + bias[t];
  float v1 = acc1*i1 + bias[t+256];
  float v2 = acc2*i2 + bias[t+512];
  y[(size_t)n*FF + t]       = v0 > 0.f ? v0 : 0.f;
  y[(size_t)n*FF + t + 256] = v1 > 0.f ? v1 : 0.f;
  y[(size_t)n*FF + t + 512] = v2 > 0.f ? v2 : 0.f;
}

// ---------- batch-norm stats ----------
__global__ __launch_bounds__(256) void bn_stats(const float* __restrict__ y,
                                                float* __restrict__ sums,
                                                float* __restrict__ sumsq){
  int t = threadIdx.x;
  float s0=0.f,s1=0.f,s2=0.f,q0=0.f,q1=0.f,q2=0.f;
  for(int n = blockIdx.x; n < NN; n += gridDim.x){
    const float* row = y + (size_t)n*FF;
    float v0 = row[t], v1 = row[t+256], v2 = row[t+512];
    s0 += v0; q0 += v0*v0;
    s1 += v1; q1 += v1*v1;
    s2 += v2; q2 += v2*v2;
  }
  atomicAdd(sums + t,       s0); atomicAdd(sumsq + t,       q0);
  atomicAdd(sums + t + 256, s1); atomicAdd(sumsq + t + 256, q1);
  atomicAdd(sums + t + 512, s2); atomicAdd(sumsq + t + 512, q2);
}

__global__ __launch_bounds__(256) void bn_final(const float* __restrict__ sums,
                                                const float* __restrict__ sumsq,
                                                const float* __restrict__ g,
                                                const float* __restrict__ be,
                                                float* __restrict__ scale,
                                                float* __restrict__ shift){
  int f = blockIdx.x*256 + threadIdx.x;
  if(f >= FF) return;
  float mu  = sums[f] * (1.f/NN);
  float var = sumsq[f] * (1.f/NN) - mu*mu;
  float sc = g[f] * rsqrtf(var + BN_EPS);
  scale[f] = sc;
  shift[f] = be[f] - mu*sc;
}

// ---------- final segment max pool ----------
__global__ __launch_bounds__(256) void init_out(unsigned* __restrict__ outEnc){
  int i = blockIdx.x*256 + threadIdx.x;
  if(i < BB*CC) outEnc[i] = FENC_NEG_INF;
}
__global__ __launch_bounds__(256) void segmax(const float* __restrict__ z,
                                              const int* __restrict__ ibatch,
                                              unsigned* __restrict__ outEnc){
  int idx = blockIdx.x*256 + threadIdx.x;
  if(idx >= NN*CC) return;
  int n = idx >> 7, c = idx & 127;
  atomicMax(outEnc + ibatch[n]*CC + c, fenc(z[idx]));
}
__global__ __launch_bounds__(256) void decode_out(const unsigned* __restrict__ outEnc,
                                                  float* __restrict__ out){
  int i = blockIdx.x*256 + threadIdx.x;
  if(i < BB*CC) out[i] = fdec(outEnc[i]);
}

extern "C" void kernel_launch(void* const* d_in, const int* in_sizes, int n_in,
                              void* d_out, int out_size, void* d_ws, size_t ws_size,
                              hipStream_t stream){
  const float* feat  = (const float*)d_in[0];
  const int*   adj   = (const int*)d_in[1];
  const int*   ibatch= (const int*)d_in[2];
  const float* W1    = (const float*)d_in[3];
  const float* atts1 = (const float*)d_in[4];
  const float* attd1 = (const float*)d_in[5];
  const float* b1    = (const float*)d_in[6];
  const float* g1    = (const float*)d_in[7];
  const float* be1   = (const float*)d_in[8];
  const float* W2    = (const float*)d_in[9];
  const float* atts2 = (const float*)d_in[10];
  const float* attd2 = (const float*)d_in[11];
  const float* b2    = (const float*)d_in[12];
  const float* g2    = (const float*)d_in[13];
  const float* be2   = (const float*)d_in[14];
  const float* linW  = (const float*)d_in[15];
  const float* linb  = (const float*)d_in[16];
  float* out = (float*)d_out;

  size_t off = 0;
  auto alloc = [&](size_t bytes) -> void* {
    void* p = (char*)d_ws + off;
    off += (bytes + 255) & ~(size_t)255;
    return p;
  };
  float*    hx      = (float*)alloc((size_t)NN*FF*4);
  float*    y       = (float*)alloc((size_t)NN*FF*4);     // also aliases featB (bf16, MP*INC)
  float*    z       = (float*)alloc((size_t)NN*CC*4);     // also aliases W1t+W2t (bf16)
  ushort_t* yB      = (ushort_t*)alloc((size_t)MP*FF*2);  // bf16 activations (BN-folded)
  ushort_t* linWt   = (ushort_t*)alloc((size_t)CC*FF*2);
  float*    a_s     = (float*)alloc((size_t)NN*6*4);
  float*    a_d     = (float*)alloc((size_t)NN*6*4);
  float*    ebuf    = (float*)alloc((size_t)ETOT*6*4);
  unsigned* mEnc    = (unsigned*)alloc((size_t)NN*6*4);
  float*    ssum    = (float*)alloc((size_t)NN*6*4);
  int*      deg     = (int*)alloc((size_t)NN*4);
  int*      row_start=(int*)alloc((size_t)(NN+1)*4);
  int*      pos     = (int*)alloc((size_t)NN*4);
  int*      csr_src = (int*)alloc((size_t)ETOT*4);
  int*      csr_eid = (int*)alloc((size_t)ETOT*4);
  float*    sums    = (float*)alloc((size_t)2*FF*4);
  float*    sumsq   = sums + FF;
  float*    scale   = (float*)alloc((size_t)FF*4);
  float*    shift   = (float*)alloc((size_t)FF*4);
  unsigned* outEnc  = (unsigned*)alloc((size_t)BB*CC*4);

  // aliases: featB in y (5.2MB < 30.7MB; y written only after gemm1 consumes featB)
  //          W1t/W2t in z (1.6MB < 5.1MB; z written only by final gemm)
  ushort_t* featB = (ushort_t*)y;
  ushort_t* W1t   = (ushort_t*)z;
  ushort_t* W2t   = W1t + (size_t)FF*INC;

  const int EB = (ETOT + 255)/256;

  // CSR build
  hipMemsetAsync(deg, 0, NN*4, stream);
  count_deg<<<EB,256,0,stream>>>(adj, deg);
  scan_deg<<<1,1024,0,stream>>>(deg, row_start, pos);
  scatter_edges<<<EB,256,0,stream>>>(adj, pos, csr_src, csr_eid);

  // weight transposes + feat convert (bf16)
  transpose_bf<<<dim3(FF/32, INC/32),256,0,stream>>>(W1, W1t, INC, FF);
  transpose_bf<<<dim3(FF/32, FF/32),256,0,stream>>>(W2, W2t, FF, FF);
  transpose_bf<<<dim3(CC/32, FF/32),256,0,stream>>>(linW, linWt, FF, CC);
  conv_bf16<<<(NN*INC/4+255)/256,256,0,stream>>>(feat, featB, NN*INC/4);

  // ---- conv1 ----
  gemm_bt<<<dim3(FF/128, MP/128),256,0,stream>>>(featB, W1t, hx, NN, FF, INC, nullptr);
  att_dots<<<NN,256,0,stream>>>(hx, atts1, attd1, a_s, a_d);
  init_ms<<<(NN*6+255)/256,256,0,stream>>>(mEnc, ssum);
  edge_phase1<<<EB,256,0,stream>>>(adj, a_s, a_d, ebuf, mEnc);
  edge_phase2<<<EB,256,0,stream>>>(adj, ebuf, mEnc, ssum);
  aggregate<<<NN,256,0,stream>>>(hx, ebuf, ssum, row_start, csr_src, csr_eid, b1, y);
  hipMemsetAsync(sums, 0, 2*FF*4, stream);
  bn_stats<<<256,256,0,stream>>>(y, sums, sumsq);
  bn_final<<<3,256,0,stream>>>(sums, sumsq, g1, be1, scale, shift);

  // ---- conv2 (BN1 folded into bf16 convert) ----
  conv_bf16_affine<<<(NN*FF/4+255)/256,256,0,stream>>>(y, scale, shift, yB, NN*FF/4);
  gemm_bt<<<dim3(FF/128, MP/128),256,0,stream>>>(yB, W2t, hx, NN, FF, FF, nullptr);
  att_dots<<<NN,256,0,stream>>>(hx, atts2, attd2, a_s, a_d);
  init_ms<<<(NN*6+255)/256,256,0,stream>>>(mEnc, ssum);
  edge_phase1<<<EB,256,0,stream>>>(adj, a_s, a_d, ebuf, mEnc);
  edge_phase2<<<EB,256,0,stream>>>(adj, ebuf, mEnc, ssum);
  aggregate<<<NN,256,0,stream>>>(hx, ebuf, ssum, row_start, csr_src, csr_eid, b2, y);
  hipMemsetAsync(sums, 0, 2*FF*4, stream);
  bn_stats<<<256,256,0,stream>>>(y, sums, sumsq);
  bn_final<<<3,256,0,stream>>>(sums, sumsq, g2, be2, scale, shift);

  // ---- linear head (BN2 folded) + global max pool ----
  conv_bf16_affine<<<(NN*FF/4+255)/256,256,0,stream>>>(y, scale, shift, yB, NN*FF/4);
  gemm_bt<<<dim3(CC/128, MP/128),256,0,stream>>>(yB, linWt, z, NN, CC, FF, linb);
  init_out<<<(BB*CC+255)/256,256,0,stream>>>(outEnc);
  segmax<<<(NN*CC+255)/256,256,0,stream>>>(z, ibatch, outEnc);
  decode_out<<<(BB*CC+255)/256,256,0,stream>>>(outEnc, out);
}